// Round 7
// baseline (1612.045 us; speedup 1.0000x reference)
//
#include <hip/hip_runtime.h>
#include <math.h>

#define IMG_H 256
#define IMG_W 256
#define IMG_SZ (IMG_H * IMG_W)
#define NP 49      /* C*p*p patch vector length */
#define HP 250     /* H - p + 1 */
#define NB 4096    /* groups per image = 64*64 */
#define NCAND 1369 /* 37*37 */
#define VRAD 18
#define CENTER (VRAD * 37 + VRAD)
#define NIMG 2
#define WSTR 55    /* bm window stride: odd -> conflict-free */

__device__ __forceinline__ float rlane(float v, int j) {
    return __int_as_float(__builtin_amdgcn_readlane(__float_as_int(v), j));
}

// Map aligned-patch coordinates (253x253, after align_corners with s=4 on a
// 250x250 grid) to original patch coordinates. Returns false for inf slots.
__device__ __forceinline__ bool align_map(int r, int c, int& ro, int& co) {
    if (r < 0 || r > 252 || c < 0 || c > 252) return false;
    if (r == 252) {
        if (c == 252) { ro = 249; co = 249; return true; }
        if (c <= 248 && (c & 3) == 0) { ro = 249; co = c; return true; }
        return false;
    }
    if (c == 252) {
        if (r <= 248 && (r & 3) == 0) { ro = r; co = 249; return true; }
        return false;
    }
    if (r >= 250 || c >= 250) return false;
    if (r == 249) {
        if (c == 249) return false;
        if ((c & 3) == 0) return false;
        ro = 249; co = c; return true;
    }
    if (c == 249) {
        if ((r & 3) == 0) return false;
        ro = r; co = 249; return true;
    }
    ro = r; co = c; return true;
}

__global__ void zero_kernel(float* __restrict__ p, int total) {
    int i = blockIdx.x * blockDim.x + threadIdx.x;
    if (i < total) p[i] = 0.0f;
}

// acc holds interleaved (num, weight) pairs per pixel.
__global__ void div_kernel(const float* __restrict__ acc, float* __restrict__ out, int total) {
    int i = blockIdx.x * blockDim.x + threadIdx.x;
    if (i < total) out[i] = acc[2 * i] / acc[2 * i + 1];
}

// 4 reference patches per 256-thread block (one wave each), sharing one staged
// union window. refp in registers; center forced during fill; selection via
// barrier-free shfl butterfly over per-lane top-2 caches.
template <int M>
__global__ __launch_bounds__(256) void bm_kernel(const float* __restrict__ img,
                                                 int* __restrict__ idx_out) {
    __shared__ float win[43 * WSTR];
    __shared__ float dist[4][NCAND];
    const int llb = blockIdx.x, kk = blockIdx.y, n = blockIdx.z;
    const float* im = img + (size_t)n * IMG_SZ;
    const int t = threadIdx.x;
    const int w = t >> 6, lane = t & 63;
    const int ll = 4 * llb + w;
    const int rr = (kk < 63) ? 4 * kk : 249;
    const int cc = (ll < 63) ? 4 * ll : 249;
    const int ar0 = 4 * kk, ac0 = 4 * ll;
    const int acb = 16 * llb;
    const int row0 = max(0, ar0 - VRAD), col0 = max(0, acb - VRAD);
    const int row1 = min(IMG_H - 1, ar0 + VRAD + 6);
    const int col1 = min(IMG_W - 1, acb + 12 + VRAD + 6);
    const int nr = row1 - row0 + 1, nc = col1 - col0 + 1;
    for (int e = t; e < nr * nc; e += 256) {
        int r = e / nc, c = e % nc;
        win[r * WSTR + c] = im[(row0 + r) * IMG_W + col0 + c];
    }
    __syncthreads();
    float rf[NP];
    {
        const float* rb = &win[(rr - row0) * WSTR + (cc - col0)];
#pragma unroll
        for (int ki = 0; ki < 7; ++ki)
#pragma unroll
            for (int kj = 0; kj < 7; ++kj) rf[ki * 7 + kj] = rb[ki * WSTR + kj];
    }
    float* dw = dist[w];
    for (int cand = lane; cand < NCAND; cand += 64) {
        const int dr = cand / 37 - VRAD, dc = cand % 37 - VRAD;
        int ro, co;
        float d;
        if (align_map(ar0 + dr, ac0 + dc, ro, co)) {
            const float* base = &win[(ro - row0) * WSTR + (co - col0)];
            float s = 0.f;
#pragma unroll
            for (int ki = 0; ki < 7; ++ki)
#pragma unroll
                for (int kj = 0; kj < 7; ++kj) {
                    float df = base[ki * WSTR + kj] - rf[ki * 7 + kj] + 1e-6f;
                    s = fmaf(df, df, s);
                }
            d = sqrtf(s);
        } else {
            d = INFINITY;
        }
        if (cand == CENTER) d = -1.0f;  // center always wins sel 0
        dw[cand] = d;
    }
    __syncthreads();
    // per-lane top-2 over the strided bucket (ascending scan => ties keep low idx)
    float v1 = INFINITY, v2 = INFINITY;
    int i1 = NCAND, i2 = NCAND;
    for (int c = lane; c < NCAND; c += 64) {
        float v = dw[c];
        if (v < v1) { v2 = v1; i2 = i1; v1 = v; i1 = c; }
        else if (v < v2) { v2 = v; i2 = c; }
    }
    int* out = idx_out + (size_t)((n * 64 + kk) * 64 + ll) * M;
    for (int sel = 0; sel < M; ++sel) {
        float gv = v1;
        int gi = i1;
#pragma unroll
        for (int off = 32; off; off >>= 1) {
            float vv = __shfl_xor(gv, off);
            int ii = __shfl_xor(gi, off);
            if (vv < gv || (vv == gv && ii < gi)) { gv = vv; gi = ii; }
        }
        if (lane == 0) {
            int dr = gi / 37 - VRAD, dc = gi % 37 - VRAD;
            out[sel] = min(rr + dr, 249) * HP + min(cc + dc, 249);
        }
        if ((gi & 63) == lane) {  // owner pops its cache; rescan only if exhausted
            dw[gi] = INFINITY;
            v1 = v2; i1 = i2; v2 = INFINITY; i2 = NCAND;
            if (i1 == NCAND) {
                for (int c = lane; c < NCAND; c += 64) {
                    float v = dw[c];
                    if (v < v1) { v2 = v1; i2 = i1; v1 = v; i1 = c; }
                    else if (v < v2) { v2 = v; i2 = c; }
                }
            }
        }
    }
}

// ONE WAVE PER GROUP, 4 independent groups per 256-thread block, ZERO barriers.
// theta = I - c*A^-1 in BOTH rounds (A = G round1, G + c*I round2, c=n*sigma^2).
// Gram: lane r holds patch row r in registers; G[r][j] via v_readlane broadcast
// (VALU pipe, no LDS) -> packed lower-triangle LDS (6.7KB). Cholesky: register
// rows (d^2 form), full row reconstructed from packed symmetry. Solves: pass A
// (identity cols -> weights), pass B (Y cols gathered from global/L1 -> X_hat,
// fused atomics). All L reads wave-uniform broadcasts at constexpr offsets.
template <int M, bool R2>
__global__ __launch_bounds__(256, 5) void denoise_kernel(
    const float* __restrict__ y, const float* __restrict__ xsrc,
    const int* __restrict__ idx, const float* __restrict__ sigma_p,
    float* __restrict__ acc) {
    constexpr int PADM = (M + 3) & ~3;  // 56 / 20
    constexpr int NCH = PADM / 4;
    // packed row offset (floats), each row 16B aligned: sum_{k<i} roundup4(k+1)
    struct RO { static constexpr int f(int i) {
        int a = i >> 2, b = i & 3; return 8 * a * (a + 1) + 4 * (a + 1) * b; } };
    constexpr int LSZ = RO::f(PADM);
    __shared__ __align__(16) float Lp[4][LSZ];
    __shared__ float cbuf[4][64];
    __shared__ __align__(16) float rdg[4][PADM];
    __shared__ float wgs[4][M];
    __shared__ int pbs[4][M];
    const int wv = threadIdx.x >> 6, lane = threadIdx.x & 63;
    const int gid = blockIdx.x * 4 + wv;
    const int n = blockIdx.y;
    const int* gx = idx + (size_t)(n * NB + gid) * M;
    const float* im = y + (size_t)n * IMG_SZ;
    const float* xim = xsrc + (size_t)n * IMG_SZ;
    float* Lw = Lp[wv];
    float* cb = cbuf[wv];
    float* rd = rdg[wv];
    float* wg = wgs[wv];
    int* pb = pbs[wv];
    const float sg = sigma_p[0];
    const float cns = 49.f * sg * sg;
    const int r = lane;
    // --- phase 1: patch bases + gram-source row gather into registers ---
    int p0 = gx[(r < M) ? r : 0];
    int base = (p0 / HP) * IMG_W + (p0 % HP);
    if (r < M) pb[r] = base;
    const float* gsrc = (R2 ? xim : im) + base;
    float pr[NP];
#pragma unroll
    for (int c = 0; c < NP; ++c) pr[c] = gsrc[(c / 7) * IMG_W + (c % 7)];
    // --- phase 2: Gram rows via readlane broadcast -> packed lower LDS ---
    const int roff = RO::f(r < PADM ? r : 0);
#pragma unroll 1
    for (int j = 0; j < M; ++j) {
        float a0 = 0.f, a1 = 0.f, a2 = 0.f, a3 = 0.f;
#pragma unroll
        for (int c = 0; c + 3 < NP; c += 4) {
            a0 = fmaf(rlane(pr[c + 0], j), pr[c + 0], a0);
            a1 = fmaf(rlane(pr[c + 1], j), pr[c + 1], a1);
            a2 = fmaf(rlane(pr[c + 2], j), pr[c + 2], a2);
            a3 = fmaf(rlane(pr[c + 3], j), pr[c + 3], a3);
        }
        a0 = fmaf(rlane(pr[48], j), pr[48], a0);
        float s = (a0 + a1) + (a2 + a3);
        if (R2 && j == r) s += cns;
        if (r < M && j <= r) Lw[roff + j] = s;
    }
    // --- phase 3: load full symmetric row from packed triangle ---
    float g[PADM];
    if (r < M) {
#pragma unroll
        for (int j = 0; j < PADM; ++j) {
            if (j >= M) {
                g[j] = 0.f;
            } else {
                int off = (j <= r) ? (roff + j) : (RO::f(j) + r);
                g[j] = Lw[off];
            }
        }
    } else {
#pragma unroll
        for (int j = 0; j < PADM; ++j) g[j] = (j == r) ? 1.f : 0.f;
    }
    // --- phase 4: d^2 register-row Cholesky (zero barriers) ---
#pragma unroll
    for (int k = 0; k < PADM - 1; ++k) {
        cb[lane] = g[k];
        float ivd = 1.f / cb[k];
        float fk = g[k] * ivd;
#pragma unroll
        for (int jb = (k + 1) / 4; jb < NCH; ++jb) {
            float4 cv = *(const float4*)&cb[4 * jb];
            if (4 * jb + 0 > k) g[4 * jb + 0] = fmaf(-fk, cv.x, g[4 * jb + 0]);
            if (4 * jb + 1 > k) g[4 * jb + 1] = fmaf(-fk, cv.y, g[4 * jb + 1]);
            if (4 * jb + 2 > k) g[4 * jb + 2] = fmaf(-fk, cv.z, g[4 * jb + 2]);
            if (4 * jb + 3 > k) g[4 * jb + 3] = fmaf(-fk, cv.w, g[4 * jb + 3]);
        }
    }
    if (r < PADM) rd[r] = 1.f / sqrtf(g[r]);  // pad rows give 1
    // --- phase 5: store scaled packed L rows ---
    if (r < PADM) {
#pragma unroll
        for (int jb = 0; jb < NCH; ++jb) {
            if (4 * jb <= r) {
                float4 rd4 = *(const float4*)&rd[4 * jb];
                float4 o;
                o.x = g[4 * jb + 0] * rd4.x;
                o.y = g[4 * jb + 1] * rd4.y;
                o.z = g[4 * jb + 2] * rd4.z;
                o.w = g[4 * jb + 3] * rd4.w;
                *(float4*)&Lw[roff + 4 * jb] = o;
            }
        }
    }
    // --- phase 6: two solve passes (A: identity -> weights; B: Y -> X_hat) ---
    const int choff = (lane < NP) ? (lane / 7) * IMG_W + (lane % 7) : 0;
    float* aA = acc + (size_t)n * IMG_SZ * 2;
#pragma unroll 1
    for (int pass = 0; pass < 2; ++pass) {
        float bb[PADM];
        if (pass == 0) {
#pragma unroll
            for (int i = 0; i < PADM; ++i) bb[i] = (i == lane) ? 1.f : 0.f;
        } else {
#pragma unroll
            for (int i = 0; i < PADM; ++i) bb[i] = (i < M) ? im[pb[i < M ? i : 0] + choff] : 0.f;
        }
        // forward: L z = b, 4-wide chunks; wave-uniform broadcast reads
#pragma unroll
        for (int ck = 0; ck < NCH; ++ck) {
            constexpr int unused = 0; (void)unused;
            const int i0 = 4 * ck;
            float L10 = Lw[RO::f(4 * ck + 1) + 4 * ck];
            float L20 = Lw[RO::f(4 * ck + 2) + 4 * ck], L21 = Lw[RO::f(4 * ck + 2) + 4 * ck + 1];
            float L30 = Lw[RO::f(4 * ck + 3) + 4 * ck], L31 = Lw[RO::f(4 * ck + 3) + 4 * ck + 1],
                  L32 = Lw[RO::f(4 * ck + 3) + 4 * ck + 2];
            float r0 = rd[i0], r1 = rd[i0 + 1], r2 = rd[i0 + 2], r3 = rd[i0 + 3];
            float b0 = bb[i0] * r0;
            float b1 = (bb[i0 + 1] - L10 * b0) * r1;
            float b2 = (bb[i0 + 2] - L20 * b0 - L21 * b1) * r2;
            float b3 = (bb[i0 + 3] - L30 * b0 - L31 * b1 - L32 * b2) * r3;
            bb[i0] = b0; bb[i0 + 1] = b1; bb[i0 + 2] = b2; bb[i0 + 3] = b3;
#pragma unroll
            for (int j = 4 * ck + 4; j < PADM; ++j) {
                float4 L4 = *(const float4*)&Lw[RO::f(j) + 4 * ck];
                bb[j] = fmaf(-L4.x, b0, fmaf(-L4.y, b1, fmaf(-L4.z, b2, fmaf(-L4.w, b3, bb[j]))));
            }
            asm volatile("" ::: "memory");  // cap load hoisting across chunks
        }
        // backward: L^T x = z, row sweeps as aligned float4 + compile-time tails
#pragma unroll
        for (int i = PADM - 1; i >= 0; --i) {
            float bbi = bb[i] * rd[i];
            bb[i] = bbi;
#pragma unroll
            for (int qb = 0; qb < i / 4; ++qb) {
                float4 L4 = *(const float4*)&Lw[RO::f(i) + 4 * qb];
                bb[4 * qb + 0] = fmaf(-L4.x, bbi, bb[4 * qb + 0]);
                bb[4 * qb + 1] = fmaf(-L4.y, bbi, bb[4 * qb + 1]);
                bb[4 * qb + 2] = fmaf(-L4.z, bbi, bb[4 * qb + 2]);
                bb[4 * qb + 3] = fmaf(-L4.w, bbi, bb[4 * qb + 3]);
            }
#pragma unroll
            for (int j = i & ~3; j < i; ++j)
                bb[j] = fmaf(-Lw[RO::f(i) + j], bbi, bb[j]);
            if ((i & 3) == 0) asm volatile("" ::: "memory");
        }
        if (pass == 0) {
            if (lane < M) {
                float s2 = 0.f;
#pragma unroll
                for (int i = 0; i < M; ++i) {
                    float th = ((i == lane) ? 1.f : 0.f) - cns * bb[i];
                    s2 = fmaf(th, th, s2);
                }
                s2 = fminf(fmaxf(s2, 1.f / (float)M), 1.f);
                wg[lane] = 1.f / s2;
            }
        } else {
            if (lane < NP) {
#pragma unroll
                for (int i = 0; i < M; ++i) {
                    int pix = pb[i] + choff;
                    float yv = im[pix];  // L1-hot re-gather
                    float xv = fmaf(-cns, bb[i], yv);
                    float wi = wg[i];
                    atomicAdd(&aA[pix * 2], xv * wi);
                    atomicAdd(&aA[pix * 2 + 1], wi);
                }
            }
        }
    }
}

extern "C" void kernel_launch(void* const* d_in, const int* in_sizes, int n_in,
                              void* d_out, int out_size, void* d_ws, size_t ws_size,
                              hipStream_t stream) {
    const float* y = (const float*)d_in[0];
    const float* sigma = (const float*)d_in[1];
    float* out = (float*)d_out;

    char* ws = (char*)d_ws;
    size_t off = 0;
    auto carve = [&](size_t bytes) {
        void* p = ws + off;
        off += (bytes + 255) & ~(size_t)255;
        return p;
    };
    int* idx1 = (int*)carve((size_t)NIMG * NB * 18 * sizeof(int));
    int* idx2 = (int*)carve((size_t)NIMG * NB * 55 * sizeof(int));
    float* acc = (float*)carve((size_t)NIMG * IMG_SZ * 2 * sizeof(float));
    float* den1 = (float*)carve((size_t)NIMG * IMG_SZ * sizeof(float));

    const int accTotal = NIMG * IMG_SZ * 2;
    const int imgTotal = NIMG * IMG_SZ;

    // Round 1: M1=18
    zero_kernel<<<(accTotal + 255) / 256, 256, 0, stream>>>(acc, accTotal);
    bm_kernel<18><<<dim3(16, 64, NIMG), 256, 0, stream>>>(y, idx1);
    denoise_kernel<18, false><<<dim3(NB / 4, NIMG), 256, 0, stream>>>(y, y, idx1, sigma, acc);
    div_kernel<<<(imgTotal + 255) / 256, 256, 0, stream>>>(acc, den1, imgTotal);

    // Round 2: M2=55
    zero_kernel<<<(accTotal + 255) / 256, 256, 0, stream>>>(acc, accTotal);
    bm_kernel<55><<<dim3(16, 64, NIMG), 256, 0, stream>>>(den1, idx2);
    denoise_kernel<55, true><<<dim3(NB / 4, NIMG), 256, 0, stream>>>(y, den1, idx2, sigma, acc);
    div_kernel<<<(imgTotal + 255) / 256, 256, 0, stream>>>(acc, out, imgTotal);
}

// Round 8
// 979.260 us; speedup vs baseline: 1.6462x; 1.6462x over previous
//
#include <hip/hip_runtime.h>
#include <math.h>

#define IMG_H 256
#define IMG_W 256
#define IMG_SZ (IMG_H * IMG_W)
#define NP 49      /* C*p*p patch vector length */
#define HP 250     /* H - p + 1 */
#define NPAT 62500 /* HP*HP patches per image */
#define NB 4096    /* groups per image = 64*64 */
#define NCAND 1369 /* 37*37 */
#define VRAD 18
#define CENTER (VRAD * 37 + VRAD)
#define NIMG 2
#define YSTR 52    /* Ys row stride: 208B, 16B aligned */
#define WSTR 55    /* bm window stride: odd -> conflict-free */

// Map aligned-patch coordinates (253x253, after align_corners with s=4 on a
// 250x250 grid) to original patch coordinates. Returns false for inf slots.
__device__ __forceinline__ bool align_map(int r, int c, int& ro, int& co) {
    if (r < 0 || r > 252 || c < 0 || c > 252) return false;
    if (r == 252) {
        if (c == 252) { ro = 249; co = 249; return true; }
        if (c <= 248 && (c & 3) == 0) { ro = 249; co = c; return true; }
        return false;
    }
    if (c == 252) {
        if (r <= 248 && (r & 3) == 0) { ro = r; co = 249; return true; }
        return false;
    }
    if (r >= 250 || c >= 250) return false;
    if (r == 249) {
        if (c == 249) return false;
        if ((c & 3) == 0) return false;
        ro = 249; co = c; return true;
    }
    if (c == 249) {
        if ((r & 3) == 0) return false;
        ro = r; co = 249; return true;
    }
    ro = r; co = c; return true;
}

__global__ void zero_kernel(float* __restrict__ p, int total) {
    int i = blockIdx.x * blockDim.x + threadIdx.x;
    if (i < total) p[i] = 0.0f;
}

// PIXEL-mode: acc holds interleaved (num, weight) pairs per pixel.
__global__ void div_kernel(const float* __restrict__ acc, float* __restrict__ out, int total) {
    int i = blockIdx.x * blockDim.x + threadIdx.x;
    if (i < total) out[i] = acc[2 * i] / acc[2 * i + 1];
}

// PATCH-mode: fold stencil. out[pix] = sum_{7x7 covering patches} Xacc / Wacc.
__global__ __launch_bounds__(256) void fold_div_kernel(const float* __restrict__ Xacc,
                                                       const float* __restrict__ Wacc,
                                                       float* __restrict__ out) {
    int e = blockIdx.x * 256 + threadIdx.x;
    if (e >= NIMG * IMG_SZ) return;
    int n = e / IMG_SZ, pix = e % IMG_SZ;
    int r = pix / IMG_W, c = pix % IMG_W;
    const float* Xn = Xacc + (size_t)n * NPAT * NP;
    const float* Wn = Wacc + (size_t)n * NPAT;
    float num = 0.f, den = 0.f;
#pragma unroll
    for (int ki = 0; ki < 7; ++ki) {
        int pr = r - ki;
        if (pr < 0 || pr > HP - 1) continue;
#pragma unroll
        for (int kj = 0; kj < 7; ++kj) {
            int pc = c - kj;
            if (pc < 0 || pc > HP - 1) continue;
            int p = pr * HP + pc;
            num += Xn[(size_t)p * NP + ki * 7 + kj];
            den += Wn[p];
        }
    }
    out[e] = num / den;
}

// 4 reference patches per 256-thread block (one wave each), sharing one staged
// union window. refp in registers; center forced during fill; selection via
// barrier-free shfl butterfly over per-lane top-2 caches.
template <int M>
__global__ __launch_bounds__(256) void bm_kernel(const float* __restrict__ img,
                                                 int* __restrict__ idx_out) {
    __shared__ float win[43 * WSTR];
    __shared__ float dist[4][NCAND];
    const int llb = blockIdx.x, kk = blockIdx.y, n = blockIdx.z;
    const float* im = img + (size_t)n * IMG_SZ;
    const int t = threadIdx.x;
    const int w = t >> 6, lane = t & 63;
    const int ll = 4 * llb + w;
    const int rr = (kk < 63) ? 4 * kk : 249;
    const int cc = (ll < 63) ? 4 * ll : 249;
    const int ar0 = 4 * kk, ac0 = 4 * ll;
    const int acb = 16 * llb;
    const int row0 = max(0, ar0 - VRAD), col0 = max(0, acb - VRAD);
    const int row1 = min(IMG_H - 1, ar0 + VRAD + 6);
    const int col1 = min(IMG_W - 1, acb + 12 + VRAD + 6);
    const int nr = row1 - row0 + 1, nc = col1 - col0 + 1;
    for (int e = t; e < nr * nc; e += 256) {
        int r = e / nc, c = e % nc;
        win[r * WSTR + c] = im[(row0 + r) * IMG_W + col0 + c];
    }
    __syncthreads();
    float rf[NP];
    {
        const float* rb = &win[(rr - row0) * WSTR + (cc - col0)];
#pragma unroll
        for (int ki = 0; ki < 7; ++ki)
#pragma unroll
            for (int kj = 0; kj < 7; ++kj) rf[ki * 7 + kj] = rb[ki * WSTR + kj];
    }
    float* dw = dist[w];
    for (int cand = lane; cand < NCAND; cand += 64) {
        const int dr = cand / 37 - VRAD, dc = cand % 37 - VRAD;
        int ro, co;
        float d;
        if (align_map(ar0 + dr, ac0 + dc, ro, co)) {
            const float* base = &win[(ro - row0) * WSTR + (co - col0)];
            float s = 0.f;
#pragma unroll
            for (int ki = 0; ki < 7; ++ki)
#pragma unroll
                for (int kj = 0; kj < 7; ++kj) {
                    float df = base[ki * WSTR + kj] - rf[ki * 7 + kj] + 1e-6f;
                    s = fmaf(df, df, s);
                }
            d = sqrtf(s);
        } else {
            d = INFINITY;
        }
        if (cand == CENTER) d = -1.0f;  // center always wins sel 0
        dw[cand] = d;
    }
    __syncthreads();
    // per-lane top-2 over the strided bucket (ascending scan => ties keep low idx)
    float v1 = INFINITY, v2 = INFINITY;
    int i1 = NCAND, i2 = NCAND;
    for (int c = lane; c < NCAND; c += 64) {
        float v = dw[c];
        if (v < v1) { v2 = v1; i2 = i1; v1 = v; i1 = c; }
        else if (v < v2) { v2 = v; i2 = c; }
    }
    int* out = idx_out + (size_t)((n * 64 + kk) * 64 + ll) * M;
    for (int sel = 0; sel < M; ++sel) {
        float gv = v1;
        int gi = i1;
#pragma unroll
        for (int off = 32; off; off >>= 1) {
            float vv = __shfl_xor(gv, off);
            int ii = __shfl_xor(gi, off);
            if (vv < gv || (vv == gv && ii < gi)) { gv = vv; gi = ii; }
        }
        if (lane == 0) {
            int dr = gi / 37 - VRAD, dc = gi % 37 - VRAD;
            out[sel] = min(rr + dr, 249) * HP + min(cc + dc, 249);
        }
        if ((gi & 63) == lane) {  // owner pops its cache; rescan only if exhausted
            dw[gi] = INFINITY;
            v1 = v2; i1 = i2; v2 = INFINITY; i2 = NCAND;
            if (i1 == NCAND) {
                for (int c = lane; c < NCAND; c += 64) {
                    float v = dw[c];
                    if (v < v1) { v2 = v1; i2 = i1; v1 = v; i1 = c; }
                    else if (v < v2) { v2 = v; i2 = c; }
                }
            }
        }
    }
}

// 128 threads (2 waves) per group. theta = I - c*A^-1 in BOTH rounds.
// Gram: slot-distributed (both waves) -> SB triangle. Cholesky: wave0 only,
// rows in REGISTERS, zero barriers. Solve: wave0 = M identity cols (weights),
// wave1 = 49 Y cols (X_hat); uniform float4 L reads. Epilogue AGGP=true:
// per-PATCH accumulators (low-contention atomics, fold later); AGGP=false:
// per-pixel interleaved (num,w) atomics (fallback).
template <int M, bool R2, bool AGGP>
__global__ __launch_bounds__(128, 2) void denoise_kernel(
    const float* __restrict__ y, const float* __restrict__ xsrc,
    const int* __restrict__ idx, const float* __restrict__ sigma_p,
    float* __restrict__ accPix, float* __restrict__ Xacc, float* __restrict__ Wacc) {
    constexpr int PADM = (M + 3) & ~3;  // 56 for M=55, 20 for M=18
    constexpr int PD = PADM + 4;        // 60 / 24: row stride in floats
    constexpr int TPK = M * (M + 1) / 2;
    constexpr int NS = (TPK + 127) / 128;
    constexpr int NCH = PADM / 4;
    __shared__ __align__(16) float Ys[M][YSTR];
    __shared__ __align__(16) float SB[PADM * PD];  // R2: Xs rows -> A -> L
    __shared__ float cbuf[64];
    __shared__ __align__(16) float rdiag[PADM];
    __shared__ float wsh[M];
    __shared__ int gix[M];
    const int b = blockIdx.x, n = blockIdx.y;
    const int t = threadIdx.x;
    const int lane = t & 63, wv = t >> 6;
    if (t < M) gix[t] = idx[(size_t)(n * NB + b) * M + t];
    __syncthreads();
    const float* im = y + (size_t)n * IMG_SZ;
    const float* xim = xsrc + (size_t)n * IMG_SZ;
    for (int e = t; e < M * YSTR; e += 128) {
        int i = e / YSTR, ch = e - i * YSTR;
        int p = gix[i];
        float v = 0.f, vx = 0.f;
        if (ch < NP) {
            int off = (p / HP + ch / 7) * IMG_W + (p % HP + ch % 7);
            v = im[off];
            if (R2) vx = xim[off];
        }
        Ys[i][ch] = v;
        if (R2) SB[i * PD + ch] = vx;  // cols [0,52); zero-padded 49..51
    }
    __syncthreads();
    const float sg = sigma_p[0];
    const float cns = 49.f * sg * sg;
    // --- Gram, slot-distributed over 128 threads, results in registers ---
    int siR[NS], sjR[NS];
    float gsum[NS];
#pragma unroll
    for (int s = 0; s < NS; ++s) {
        int e = t + 128 * s;
        if (e < TPK) {
            int i = (int)((sqrtf(8.f * e + 1.f) - 1.f) * 0.5f);
            while ((i + 1) * (i + 2) / 2 <= e) ++i;
            while (i * (i + 1) / 2 > e) --i;
            siR[s] = i;
            sjR[s] = e - i * (i + 1) / 2;
        } else {
            siR[s] = -1;
            sjR[s] = 0;
        }
    }
#pragma unroll
    for (int s = 0; s < NS; ++s) {
        float sum = 0.f;
        if (siR[s] >= 0) {
            const float* Pi = R2 ? &SB[siR[s] * PD] : &Ys[siR[s]][0];
            const float* Pj = R2 ? &SB[sjR[s] * PD] : &Ys[sjR[s]][0];
#pragma unroll
            for (int q = 0; q < 13; ++q) {
                float4 a = *(const float4*)(Pi + 4 * q);
                float4 c4 = *(const float4*)(Pj + 4 * q);
                sum = fmaf(a.x, c4.x, sum);
                sum = fmaf(a.y, c4.y, sum);
                sum = fmaf(a.z, c4.z, sum);
                sum = fmaf(a.w, c4.w, sum);
            }
            if (R2 && siR[s] == sjR[s]) sum += cns;
        }
        gsum[s] = sum;
    }
    __syncthreads();  // all Gram reads of SB done before overlay
#pragma unroll
    for (int s = 0; s < NS; ++s)
        if (siR[s] >= 0) {
            SB[siR[s] * PD + sjR[s]] = gsum[s];
            SB[sjR[s] * PD + siR[s]] = gsum[s];  // mirror: full symmetric rows
        }
    __syncthreads();
    // --- wave0: register-row Cholesky (d^2 form), zero barriers ---
    if (wv == 0) {
        float g[PADM];
        const int ri = (lane < M) ? lane : 0;
#pragma unroll
        for (int jb = 0; jb < NCH; ++jb) {
            float4 v4 = *(const float4*)&SB[ri * PD + 4 * jb];
            g[4 * jb] = v4.x; g[4 * jb + 1] = v4.y; g[4 * jb + 2] = v4.z; g[4 * jb + 3] = v4.w;
        }
        if (lane >= M) {
#pragma unroll
            for (int j = 0; j < PADM; ++j) g[j] = (j == lane) ? 1.f : 0.f;
        }
#pragma unroll
        for (int k = 0; k < PADM - 1; ++k) {
            cbuf[lane] = g[k];
            float ivd = 1.f / cbuf[k];
            float fk = g[k] * ivd;
#pragma unroll
            for (int jb = (k + 1) / 4; jb < NCH; ++jb) {
                float4 cv = *(const float4*)&cbuf[4 * jb];
                if (4 * jb + 0 > k) g[4 * jb + 0] = fmaf(-fk, cv.x, g[4 * jb + 0]);
                if (4 * jb + 1 > k) g[4 * jb + 1] = fmaf(-fk, cv.y, g[4 * jb + 1]);
                if (4 * jb + 2 > k) g[4 * jb + 2] = fmaf(-fk, cv.z, g[4 * jb + 2]);
                if (4 * jb + 3 > k) g[4 * jb + 3] = fmaf(-fk, cv.w, g[4 * jb + 3]);
            }
        }
        if (lane < PADM) rdiag[lane] = (lane < M) ? 1.f / sqrtf(g[lane]) : 1.f;
        // scale row by rdiag[col] and store L (only j<=i ever read by solves)
        if (lane < PADM) {
#pragma unroll
            for (int jb = 0; jb < NCH; ++jb) {
                float4 rd = *(const float4*)&rdiag[4 * jb];
                float4 o;
                o.x = g[4 * jb] * rd.x; o.y = g[4 * jb + 1] * rd.y;
                o.z = g[4 * jb + 2] * rd.z; o.w = g[4 * jb + 3] * rd.w;
                *(float4*)&SB[lane * PD + 4 * jb] = o;
            }
        }
    }
    __syncthreads();
    // --- solves: wave0 lane -> identity col (weights), wave1 lane -> Y col ---
    const bool isId = (wv == 0) && (lane < M);
    const bool isY = (wv == 1) && (lane < NP);
    const int ch = (wv == 1 && lane < NP) ? lane : 0;
    float bb[PADM];
    if (wv == 1) {
#pragma unroll
        for (int i = 0; i < PADM; ++i) bb[i] = (i < M) ? Ys[i][ch] : 0.f;
    } else {
#pragma unroll
        for (int i = 0; i < PADM; ++i) bb[i] = (i == lane) ? 1.f : 0.f;
    }
    // forward: L z = b, 4-wide chunks; all L loads wave-uniform broadcasts
#pragma unroll
    for (int ck = 0; ck < NCH; ++ck) {
        const int i0 = 4 * ck;
        float L10 = SB[(i0 + 1) * PD + i0];
        float L20 = SB[(i0 + 2) * PD + i0], L21 = SB[(i0 + 2) * PD + i0 + 1];
        float L30 = SB[(i0 + 3) * PD + i0], L31 = SB[(i0 + 3) * PD + i0 + 1],
              L32 = SB[(i0 + 3) * PD + i0 + 2];
        float b0 = bb[i0] * rdiag[i0];
        float b1 = (bb[i0 + 1] - L10 * b0) * rdiag[i0 + 1];
        float b2 = (bb[i0 + 2] - L20 * b0 - L21 * b1) * rdiag[i0 + 2];
        float b3 = (bb[i0 + 3] - L30 * b0 - L31 * b1 - L32 * b2) * rdiag[i0 + 3];
        bb[i0] = b0; bb[i0 + 1] = b1; bb[i0 + 2] = b2; bb[i0 + 3] = b3;
#pragma unroll
        for (int j = i0 + 4; j < PADM; ++j) {
            float4 L4 = *(const float4*)&SB[j * PD + i0];
            bb[j] = fmaf(-L4.x, b0, fmaf(-L4.y, b1, fmaf(-L4.z, b2, fmaf(-L4.w, b3, bb[j]))));
        }
        asm volatile("" ::: "memory");  // cap load hoisting across chunks
    }
    // backward: L^T x = z, row sweeps as aligned float4 + compile-time tails
#pragma unroll
    for (int i = PADM - 1; i >= 0; --i) {
        float bbi = bb[i] * rdiag[i];
        bb[i] = bbi;
#pragma unroll
        for (int qb = 0; qb < i / 4; ++qb) {
            float4 L4 = *(const float4*)&SB[i * PD + 4 * qb];
            bb[4 * qb + 0] = fmaf(-L4.x, bbi, bb[4 * qb + 0]);
            bb[4 * qb + 1] = fmaf(-L4.y, bbi, bb[4 * qb + 1]);
            bb[4 * qb + 2] = fmaf(-L4.z, bbi, bb[4 * qb + 2]);
            bb[4 * qb + 3] = fmaf(-L4.w, bbi, bb[4 * qb + 3]);
        }
#pragma unroll
        for (int j = i & ~3; j < i; ++j)
            bb[j] = fmaf(-SB[i * PD + j], bbi, bb[j]);
        if ((i & 3) == 0) asm volatile("" ::: "memory");
    }
    // --- weights (theta symmetric via identity columns) ---
    float wloc = 0.f;
    if (isId) {
        float s2 = 0.f;
#pragma unroll
        for (int i = 0; i < M; ++i) {
            float th = ((i == lane) ? 1.f : 0.f) - cns * bb[i];
            s2 = fmaf(th, th, s2);
        }
        s2 = fminf(fmaxf(s2, 1.f / (float)M), 1.f);
        wloc = 1.f / s2;
        wsh[lane] = wloc;
    }
    if (!AGGP && isY) {
#pragma unroll
        for (int i = 0; i < M; ++i) Ys[i][ch] = fmaf(-cns, bb[i], Ys[i][ch]);
    }
    __syncthreads();
    if (AGGP) {
        // per-PATCH scatter: ~7-way contention, lane-coalesced Xacc lines
        if (isId) atomicAdd(&Wacc[(size_t)n * NPAT + gix[lane]], wloc);
        if (isY) {
#pragma unroll
            for (int i = 0; i < M; ++i) {
                float xv = fmaf(-cns, bb[i], Ys[i][ch]);
                atomicAdd(&Xacc[((size_t)n * NPAT + gix[i]) * NP + ch], xv * wsh[i]);
            }
        }
    } else {
        float* aA = accPix + (size_t)n * IMG_SZ * 2;
        for (int e = t; e < M * NP; e += 128) {
            int i = e / NP, c2 = e % NP;
            int p = gix[i];
            int pix = (p / HP + c2 / 7) * IMG_W + (p % HP + c2 % 7);
            float wi = wsh[i];
            atomicAdd(&aA[pix * 2], Ys[i][c2] * wi);
            atomicAdd(&aA[pix * 2 + 1], wi);
        }
    }
}

extern "C" void kernel_launch(void* const* d_in, const int* in_sizes, int n_in,
                              void* d_out, int out_size, void* d_ws, size_t ws_size,
                              hipStream_t stream) {
    const float* y = (const float*)d_in[0];
    const float* sigma = (const float*)d_in[1];
    float* out = (float*)d_out;

    char* ws = (char*)d_ws;
    size_t off = 0;
    auto carve = [&](size_t bytes) {
        void* p = ws + off;
        off += (bytes + 255) & ~(size_t)255;
        return p;
    };
    int* idx1 = (int*)carve((size_t)NIMG * NB * 18 * sizeof(int));
    int* idx2 = (int*)carve((size_t)NIMG * NB * 55 * sizeof(int));
    float* accPix = (float*)carve((size_t)NIMG * IMG_SZ * 2 * sizeof(float));
    float* den1 = (float*)carve((size_t)NIMG * IMG_SZ * sizeof(float));
    // PATCH-mode accumulators: X then W contiguous (zeroed together)
    const size_t xw_floats = (size_t)NIMG * NPAT * (NP + 1);
    float* Xacc = (float*)carve(xw_floats * sizeof(float));
    float* Wacc = Xacc + (size_t)NIMG * NPAT * NP;
    const bool patchMode = (off <= ws_size);

    const int imgTotal = NIMG * IMG_SZ;

    if (patchMode) {
        const int xwTotal = (int)xw_floats;
        // Round 1: M1=18
        zero_kernel<<<(xwTotal + 255) / 256, 256, 0, stream>>>(Xacc, xwTotal);
        bm_kernel<18><<<dim3(16, 64, NIMG), 256, 0, stream>>>(y, idx1);
        denoise_kernel<18, false, true><<<dim3(NB, NIMG), 128, 0, stream>>>(
            y, y, idx1, sigma, accPix, Xacc, Wacc);
        fold_div_kernel<<<(imgTotal + 255) / 256, 256, 0, stream>>>(Xacc, Wacc, den1);
        // Round 2: M2=55
        zero_kernel<<<(xwTotal + 255) / 256, 256, 0, stream>>>(Xacc, xwTotal);
        bm_kernel<55><<<dim3(16, 64, NIMG), 256, 0, stream>>>(den1, idx2);
        denoise_kernel<55, true, true><<<dim3(NB, NIMG), 128, 0, stream>>>(
            y, den1, idx2, sigma, accPix, Xacc, Wacc);
        fold_div_kernel<<<(imgTotal + 255) / 256, 256, 0, stream>>>(Xacc, Wacc, out);
    } else {
        const int accTotal = NIMG * IMG_SZ * 2;
        // Round 1: M1=18
        zero_kernel<<<(accTotal + 255) / 256, 256, 0, stream>>>(accPix, accTotal);
        bm_kernel<18><<<dim3(16, 64, NIMG), 256, 0, stream>>>(y, idx1);
        denoise_kernel<18, false, false><<<dim3(NB, NIMG), 128, 0, stream>>>(
            y, y, idx1, sigma, accPix, Xacc, Wacc);
        div_kernel<<<(imgTotal + 255) / 256, 256, 0, stream>>>(accPix, den1, imgTotal);
        // Round 2: M2=55
        zero_kernel<<<(accTotal + 255) / 256, 256, 0, stream>>>(accPix, accTotal);
        bm_kernel<55><<<dim3(16, 64, NIMG), 256, 0, stream>>>(den1, idx2);
        denoise_kernel<55, true, false><<<dim3(NB, NIMG), 128, 0, stream>>>(
            y, den1, idx2, sigma, accPix, Xacc, Wacc);
        div_kernel<<<(imgTotal + 255) / 256, 256, 0, stream>>>(accPix, out, imgTotal);
    }
}

// Round 9
// 960.610 us; speedup vs baseline: 1.6781x; 1.0194x over previous
//
#include <hip/hip_runtime.h>
#include <math.h>

#define IMG_H 256
#define IMG_W 256
#define IMG_SZ (IMG_H * IMG_W)
#define NP 49      /* C*p*p patch vector length */
#define HP 250     /* H - p + 1 */
#define NPAT 62500 /* HP*HP patches per image */
#define NB 4096    /* groups per image = 64*64 */
#define NCAND 1369 /* 37*37 */
#define VRAD 18
#define CENTER (VRAD * 37 + VRAD)
#define NIMG 2
#define YSTR 52    /* patch row stride: 208B, 16B aligned */
#define WSTR 55    /* bm window stride: odd -> conflict-free */

// Map aligned-patch coordinates (253x253, after align_corners with s=4 on a
// 250x250 grid) to original patch coordinates. Returns false for inf slots.
__device__ __forceinline__ bool align_map(int r, int c, int& ro, int& co) {
    if (r < 0 || r > 252 || c < 0 || c > 252) return false;
    if (r == 252) {
        if (c == 252) { ro = 249; co = 249; return true; }
        if (c <= 248 && (c & 3) == 0) { ro = 249; co = c; return true; }
        return false;
    }
    if (c == 252) {
        if (r <= 248 && (r & 3) == 0) { ro = r; co = 249; return true; }
        return false;
    }
    if (r >= 250 || c >= 250) return false;
    if (r == 249) {
        if (c == 249) return false;
        if ((c & 3) == 0) return false;
        ro = 249; co = c; return true;
    }
    if (c == 249) {
        if ((r & 3) == 0) return false;
        ro = r; co = 249; return true;
    }
    ro = r; co = c; return true;
}

__global__ void zero_kernel(float* __restrict__ p, int total) {
    int i = blockIdx.x * blockDim.x + threadIdx.x;
    if (i < total) p[i] = 0.0f;
}

// PIXEL-mode: acc holds interleaved (num, weight) pairs per pixel.
__global__ void div_kernel(const float* __restrict__ acc, float* __restrict__ out, int total) {
    int i = blockIdx.x * blockDim.x + threadIdx.x;
    if (i < total) out[i] = acc[2 * i] / acc[2 * i + 1];
}

// PATCH-mode: fold stencil. out[pix] = sum_{7x7 covering patches} Xacc / Wacc.
__global__ __launch_bounds__(256) void fold_div_kernel(const float* __restrict__ Xacc,
                                                       const float* __restrict__ Wacc,
                                                       float* __restrict__ out) {
    int e = blockIdx.x * 256 + threadIdx.x;
    if (e >= NIMG * IMG_SZ) return;
    int n = e / IMG_SZ, pix = e % IMG_SZ;
    int r = pix / IMG_W, c = pix % IMG_W;
    const float* Xn = Xacc + (size_t)n * NPAT * NP;
    const float* Wn = Wacc + (size_t)n * NPAT;
    float num = 0.f, den = 0.f;
#pragma unroll
    for (int ki = 0; ki < 7; ++ki) {
        int pr = r - ki;
        if (pr < 0 || pr > HP - 1) continue;
#pragma unroll
        for (int kj = 0; kj < 7; ++kj) {
            int pc = c - kj;
            if (pc < 0 || pc > HP - 1) continue;
            int p = pr * HP + pc;
            num += Xn[(size_t)p * NP + ki * 7 + kj];
            den += Wn[p];
        }
    }
    out[e] = num / den;
}

// 4 reference patches per 256-thread block (one wave each), sharing one staged
// union window. refp in registers; center forced during fill; selection via
// barrier-free shfl butterfly over per-lane top-2 caches.
template <int M>
__global__ __launch_bounds__(256) void bm_kernel(const float* __restrict__ img,
                                                 int* __restrict__ idx_out) {
    __shared__ float win[43 * WSTR];
    __shared__ float dist[4][NCAND];
    const int llb = blockIdx.x, kk = blockIdx.y, n = blockIdx.z;
    const float* im = img + (size_t)n * IMG_SZ;
    const int t = threadIdx.x;
    const int w = t >> 6, lane = t & 63;
    const int ll = 4 * llb + w;
    const int rr = (kk < 63) ? 4 * kk : 249;
    const int cc = (ll < 63) ? 4 * ll : 249;
    const int ar0 = 4 * kk, ac0 = 4 * ll;
    const int acb = 16 * llb;
    const int row0 = max(0, ar0 - VRAD), col0 = max(0, acb - VRAD);
    const int row1 = min(IMG_H - 1, ar0 + VRAD + 6);
    const int col1 = min(IMG_W - 1, acb + 12 + VRAD + 6);
    const int nr = row1 - row0 + 1, nc = col1 - col0 + 1;
    for (int e = t; e < nr * nc; e += 256) {
        int r = e / nc, c = e % nc;
        win[r * WSTR + c] = im[(row0 + r) * IMG_W + col0 + c];
    }
    __syncthreads();
    float rf[NP];
    {
        const float* rb = &win[(rr - row0) * WSTR + (cc - col0)];
#pragma unroll
        for (int ki = 0; ki < 7; ++ki)
#pragma unroll
            for (int kj = 0; kj < 7; ++kj) rf[ki * 7 + kj] = rb[ki * WSTR + kj];
    }
    float* dw = dist[w];
    for (int cand = lane; cand < NCAND; cand += 64) {
        const int dr = cand / 37 - VRAD, dc = cand % 37 - VRAD;
        int ro, co;
        float d;
        if (align_map(ar0 + dr, ac0 + dc, ro, co)) {
            const float* base = &win[(ro - row0) * WSTR + (co - col0)];
            float s = 0.f;
#pragma unroll
            for (int ki = 0; ki < 7; ++ki)
#pragma unroll
                for (int kj = 0; kj < 7; ++kj) {
                    float df = base[ki * WSTR + kj] - rf[ki * 7 + kj] + 1e-6f;
                    s = fmaf(df, df, s);
                }
            d = sqrtf(s);
        } else {
            d = INFINITY;
        }
        if (cand == CENTER) d = -1.0f;  // center always wins sel 0
        dw[cand] = d;
    }
    __syncthreads();
    // per-lane top-2 over the strided bucket (ascending scan => ties keep low idx)
    float v1 = INFINITY, v2 = INFINITY;
    int i1 = NCAND, i2 = NCAND;
    for (int c = lane; c < NCAND; c += 64) {
        float v = dw[c];
        if (v < v1) { v2 = v1; i2 = i1; v1 = v; i1 = c; }
        else if (v < v2) { v2 = v; i2 = c; }
    }
    int* out = idx_out + (size_t)((n * 64 + kk) * 64 + ll) * M;
    for (int sel = 0; sel < M; ++sel) {
        float gv = v1;
        int gi = i1;
#pragma unroll
        for (int off = 32; off; off >>= 1) {
            float vv = __shfl_xor(gv, off);
            int ii = __shfl_xor(gi, off);
            if (vv < gv || (vv == gv && ii < gi)) { gv = vv; gi = ii; }
        }
        if (lane == 0) {
            int dr = gi / 37 - VRAD, dc = gi % 37 - VRAD;
            out[sel] = min(rr + dr, 249) * HP + min(cc + dc, 249);
        }
        if ((gi & 63) == lane) {  // owner pops its cache; rescan only if exhausted
            dw[gi] = INFINITY;
            v1 = v2; i1 = i2; v2 = INFINITY; i2 = NCAND;
            if (i1 == NCAND) {
                for (int c = lane; c < NCAND; c += 64) {
                    float v = dw[c];
                    if (v < v1) { v2 = v1; i2 = i1; v1 = v; i1 = c; }
                    else if (v < v2) { v2 = v; i2 = c; }
                }
            }
        }
    }
}

// 128 threads (2 waves) per group. theta = I - c*A^-1 in BOTH rounds.
// LDS union SU = [packed-L (16B-aligned rows) | Ys rows]: R2 stages Xs over
// the L region during Gram (L written after the sync), Ys staged post-Gram.
// Peak LDS ~19KB -> 8 blocks/CU. Gram slot-distributed -> packed A; Cholesky
// wave0-only, rows in registers (d^2 form, row reconstructed from packed
// symmetry), zero barriers; scaled packed L stored once. Solve: wave0 = M
// identity cols (weights), wave1 = 49 Y cols (X_hat); uniform broadcast
// float4 L reads at constexpr packed offsets. Epilogue: per-PATCH atomics
// (AGGP) or per-pixel fallback.
template <int M, bool R2, bool AGGP>
__global__ __launch_bounds__(128, 2) void denoise_kernel(
    const float* __restrict__ y, const float* __restrict__ xsrc,
    const int* __restrict__ idx, const float* __restrict__ sigma_p,
    float* __restrict__ accPix, float* __restrict__ Xacc, float* __restrict__ Wacc) {
    constexpr int PADM = (M + 3) & ~3;  // 56 for M=55, 20 for M=18
    constexpr int NCH = PADM / 4;
    constexpr int TPK = M * (M + 1) / 2;
    constexpr int NS = (TPK + 127) / 128;
    // packed row offset (floats), each row 16B aligned: sum_{k<i} roundup4(k+1)
    struct RO { static constexpr int f(int i) {
        int a = i >> 2, b = i & 3; return 8 * a * (a + 1) + 4 * (a + 1) * b; } };
    constexpr int LSZ = RO::f(PADM);
    constexpr int YOFF = LSZ;            // Ys rows live after the packed L
    constexpr int UN = LSZ + M * YSTR;   // union size (floats)
    __shared__ __align__(16) float SU[UN];
    __shared__ float cbuf[64];
    __shared__ __align__(16) float rdiag[PADM];
    __shared__ float wsh[M];
    __shared__ int gix[M];
    const int b = blockIdx.x, n = blockIdx.y;
    const int t = threadIdx.x;
    const int lane = t & 63, wv = t >> 6;
    if (t < M) gix[t] = idx[(size_t)(n * NB + b) * M + t];
    __syncthreads();
    const float* im = y + (size_t)n * IMG_SZ;
    const float* xim = xsrc + (size_t)n * IMG_SZ;
    // --- stage Gram source rows (R1: Ys at YOFF; R2: Xs at 0) ---
    {
        const float* src = R2 ? xim : im;
        float* dst = R2 ? &SU[0] : &SU[YOFF];
        for (int e = t; e < M * YSTR; e += 128) {
            int i = e / YSTR, ch = e - i * YSTR;
            float v = 0.f;
            if (ch < NP) {
                int p = gix[i];
                v = src[(p / HP + ch / 7) * IMG_W + (p % HP + ch % 7)];
            }
            dst[i * YSTR + ch] = v;
        }
    }
    __syncthreads();
    const float sg = sigma_p[0];
    const float cns = 49.f * sg * sg;
    // --- Gram, slot-distributed over 128 threads, results in registers ---
    int siR[NS], sjR[NS];
    float gsum[NS];
#pragma unroll
    for (int s = 0; s < NS; ++s) {
        int e = t + 128 * s;
        if (e < TPK) {
            int i = (int)((sqrtf(8.f * e + 1.f) - 1.f) * 0.5f);
            while ((i + 1) * (i + 2) / 2 <= e) ++i;
            while (i * (i + 1) / 2 > e) --i;
            siR[s] = i;
            sjR[s] = e - i * (i + 1) / 2;
        } else {
            siR[s] = -1;
            sjR[s] = 0;
        }
    }
    {
        const float* base = R2 ? &SU[0] : &SU[YOFF];
#pragma unroll
        for (int s = 0; s < NS; ++s) {
            float sum = 0.f;
            if (siR[s] >= 0) {
                const float* Pi = base + siR[s] * YSTR;
                const float* Pj = base + sjR[s] * YSTR;
#pragma unroll
                for (int q = 0; q < 13; ++q) {
                    float4 a = *(const float4*)(Pi + 4 * q);
                    float4 c4 = *(const float4*)(Pj + 4 * q);
                    sum = fmaf(a.x, c4.x, sum);
                    sum = fmaf(a.y, c4.y, sum);
                    sum = fmaf(a.z, c4.z, sum);
                    sum = fmaf(a.w, c4.w, sum);
                }
                if (R2 && siR[s] == sjR[s]) sum += cns;
            }
            gsum[s] = sum;
        }
    }
    __syncthreads();  // all Gram reads complete before A overlays Xs region
    // --- write packed A; R2: stage Ys (overwrites dead Xs tail) ---
#pragma unroll
    for (int s = 0; s < NS; ++s)
        if (siR[s] >= 0) SU[RO::f(siR[s]) + sjR[s]] = gsum[s];
    if (R2) {
        for (int e = t; e < M * YSTR; e += 128) {
            int i = e / YSTR, ch = e - i * YSTR;
            float v = 0.f;
            if (ch < NP) {
                int p = gix[i];
                v = im[(p / HP + ch / 7) * IMG_W + (p % HP + ch % 7)];
            }
            SU[YOFF + i * YSTR + ch] = v;
        }
    }
    __syncthreads();
    // --- wave0: register-row Cholesky (d^2 form), zero barriers ---
    if (wv == 0) {
        float g[PADM];
        if (lane < M) {
#pragma unroll
            for (int j = 0; j < PADM; ++j) {
                if (j >= M) g[j] = 0.f;
                else g[j] = (j <= lane) ? SU[RO::f(lane) + j] : SU[RO::f(j) + lane];
            }
        } else {
#pragma unroll
            for (int j = 0; j < PADM; ++j) g[j] = (j == lane) ? 1.f : 0.f;
        }
#pragma unroll
        for (int k = 0; k < PADM - 1; ++k) {
            cbuf[lane] = g[k];
            float ivd = 1.f / cbuf[k];
            float fk = g[k] * ivd;
#pragma unroll
            for (int jb = (k + 1) / 4; jb < NCH; ++jb) {
                float4 cv = *(const float4*)&cbuf[4 * jb];
                if (4 * jb + 0 > k) g[4 * jb + 0] = fmaf(-fk, cv.x, g[4 * jb + 0]);
                if (4 * jb + 1 > k) g[4 * jb + 1] = fmaf(-fk, cv.y, g[4 * jb + 1]);
                if (4 * jb + 2 > k) g[4 * jb + 2] = fmaf(-fk, cv.z, g[4 * jb + 2]);
                if (4 * jb + 3 > k) g[4 * jb + 3] = fmaf(-fk, cv.w, g[4 * jb + 3]);
            }
        }
        if (lane < PADM) rdiag[lane] = (lane < M) ? 1.f / sqrtf(g[lane]) : 1.f;
        // scale row by rdiag[col], store packed L (only j<=i read by solves)
        if (lane < PADM) {
#pragma unroll
            for (int jb = 0; jb < NCH; ++jb) {
                if (4 * jb <= lane) {
                    float4 rd4 = *(const float4*)&rdiag[4 * jb];
                    float4 o;
                    o.x = g[4 * jb + 0] * rd4.x;
                    o.y = g[4 * jb + 1] * rd4.y;
                    o.z = g[4 * jb + 2] * rd4.z;
                    o.w = g[4 * jb + 3] * rd4.w;
                    *(float4*)&SU[RO::f(lane) + 4 * jb] = o;
                }
            }
        }
    }
    __syncthreads();
    // --- solves: wave0 lane -> identity col (weights), wave1 lane -> Y col ---
    const bool isId = (wv == 0) && (lane < M);
    const bool isY = (wv == 1) && (lane < NP);
    const int ch = (wv == 1 && lane < NP) ? lane : 0;
    float bb[PADM];
    if (wv == 1) {
#pragma unroll
        for (int i = 0; i < PADM; ++i) bb[i] = (i < M) ? SU[YOFF + i * YSTR + ch] : 0.f;
    } else {
#pragma unroll
        for (int i = 0; i < PADM; ++i) bb[i] = (i == lane) ? 1.f : 0.f;
    }
    // forward: L z = b, 4-wide chunks; all L loads wave-uniform broadcasts
#pragma unroll
    for (int ck = 0; ck < NCH; ++ck) {
        const int i0 = 4 * ck;
        float L10 = SU[RO::f(4 * ck + 1) + 4 * ck];
        float L20 = SU[RO::f(4 * ck + 2) + 4 * ck], L21 = SU[RO::f(4 * ck + 2) + 4 * ck + 1];
        float L30 = SU[RO::f(4 * ck + 3) + 4 * ck], L31 = SU[RO::f(4 * ck + 3) + 4 * ck + 1],
              L32 = SU[RO::f(4 * ck + 3) + 4 * ck + 2];
        float b0 = bb[i0] * rdiag[i0];
        float b1 = (bb[i0 + 1] - L10 * b0) * rdiag[i0 + 1];
        float b2 = (bb[i0 + 2] - L20 * b0 - L21 * b1) * rdiag[i0 + 2];
        float b3 = (bb[i0 + 3] - L30 * b0 - L31 * b1 - L32 * b2) * rdiag[i0 + 3];
        bb[i0] = b0; bb[i0 + 1] = b1; bb[i0 + 2] = b2; bb[i0 + 3] = b3;
#pragma unroll
        for (int j = 4 * ck + 4; j < PADM; ++j) {
            float4 L4 = *(const float4*)&SU[RO::f(j) + 4 * ck];
            bb[j] = fmaf(-L4.x, b0, fmaf(-L4.y, b1, fmaf(-L4.z, b2, fmaf(-L4.w, b3, bb[j]))));
        }
        if (ck & 1) asm volatile("" ::: "memory");  // 2-chunk load-hoist window
    }
    // backward: L^T x = z, row sweeps as aligned float4 + compile-time tails
#pragma unroll
    for (int i = PADM - 1; i >= 0; --i) {
        float bbi = bb[i] * rdiag[i];
        bb[i] = bbi;
#pragma unroll
        for (int qb = 0; qb < i / 4; ++qb) {
            float4 L4 = *(const float4*)&SU[RO::f(i) + 4 * qb];
            bb[4 * qb + 0] = fmaf(-L4.x, bbi, bb[4 * qb + 0]);
            bb[4 * qb + 1] = fmaf(-L4.y, bbi, bb[4 * qb + 1]);
            bb[4 * qb + 2] = fmaf(-L4.z, bbi, bb[4 * qb + 2]);
            bb[4 * qb + 3] = fmaf(-L4.w, bbi, bb[4 * qb + 3]);
        }
#pragma unroll
        for (int j = i & ~3; j < i; ++j)
            bb[j] = fmaf(-SU[RO::f(i) + j], bbi, bb[j]);
        if ((i & 7) == 0) asm volatile("" ::: "memory");  // 8-row hoist window
    }
    // --- weights (theta symmetric via identity columns) ---
    float wloc = 0.f;
    if (isId) {
        float s2 = 0.f;
#pragma unroll
        for (int i = 0; i < M; ++i) {
            float th = ((i == lane) ? 1.f : 0.f) - cns * bb[i];
            s2 = fmaf(th, th, s2);
        }
        s2 = fminf(fmaxf(s2, 1.f / (float)M), 1.f);
        wloc = 1.f / s2;
        wsh[lane] = wloc;
    }
    if (!AGGP && isY) {
#pragma unroll
        for (int i = 0; i < M; ++i)
            SU[YOFF + i * YSTR + ch] = fmaf(-cns, bb[i], SU[YOFF + i * YSTR + ch]);
    }
    __syncthreads();
    if (AGGP) {
        // per-PATCH scatter: ~7-way contention, lane-coalesced Xacc lines
        if (isId) atomicAdd(&Wacc[(size_t)n * NPAT + gix[lane]], wloc);
        if (isY) {
#pragma unroll
            for (int i = 0; i < M; ++i) {
                float xv = fmaf(-cns, bb[i], SU[YOFF + i * YSTR + ch]);
                atomicAdd(&Xacc[((size_t)n * NPAT + gix[i]) * NP + ch], xv * wsh[i]);
            }
        }
    } else {
        float* aA = accPix + (size_t)n * IMG_SZ * 2;
        for (int e = t; e < M * NP; e += 128) {
            int i = e / NP, c2 = e % NP;
            int p = gix[i];
            int pix = (p / HP + c2 / 7) * IMG_W + (p % HP + c2 % 7);
            float wi = wsh[i];
            atomicAdd(&aA[pix * 2], SU[YOFF + i * YSTR + c2] * wi);
            atomicAdd(&aA[pix * 2 + 1], wi);
        }
    }
}

extern "C" void kernel_launch(void* const* d_in, const int* in_sizes, int n_in,
                              void* d_out, int out_size, void* d_ws, size_t ws_size,
                              hipStream_t stream) {
    const float* y = (const float*)d_in[0];
    const float* sigma = (const float*)d_in[1];
    float* out = (float*)d_out;

    char* ws = (char*)d_ws;
    size_t off = 0;
    auto carve = [&](size_t bytes) {
        void* p = ws + off;
        off += (bytes + 255) & ~(size_t)255;
        return p;
    };
    int* idx1 = (int*)carve((size_t)NIMG * NB * 18 * sizeof(int));
    int* idx2 = (int*)carve((size_t)NIMG * NB * 55 * sizeof(int));
    float* accPix = (float*)carve((size_t)NIMG * IMG_SZ * 2 * sizeof(float));
    float* den1 = (float*)carve((size_t)NIMG * IMG_SZ * sizeof(float));
    // PATCH-mode accumulators: X then W contiguous (zeroed together)
    const size_t xw_floats = (size_t)NIMG * NPAT * (NP + 1);
    float* Xacc = (float*)carve(xw_floats * sizeof(float));
    float* Wacc = Xacc + (size_t)NIMG * NPAT * NP;
    const bool patchMode = (off <= ws_size);

    const int imgTotal = NIMG * IMG_SZ;

    if (patchMode) {
        const int xwTotal = (int)xw_floats;
        // Round 1: M1=18
        zero_kernel<<<(xwTotal + 255) / 256, 256, 0, stream>>>(Xacc, xwTotal);
        bm_kernel<18><<<dim3(16, 64, NIMG), 256, 0, stream>>>(y, idx1);
        denoise_kernel<18, false, true><<<dim3(NB, NIMG), 128, 0, stream>>>(
            y, y, idx1, sigma, accPix, Xacc, Wacc);
        fold_div_kernel<<<(imgTotal + 255) / 256, 256, 0, stream>>>(Xacc, Wacc, den1);
        // Round 2: M2=55
        zero_kernel<<<(xwTotal + 255) / 256, 256, 0, stream>>>(Xacc, xwTotal);
        bm_kernel<55><<<dim3(16, 64, NIMG), 256, 0, stream>>>(den1, idx2);
        denoise_kernel<55, true, true><<<dim3(NB, NIMG), 128, 0, stream>>>(
            y, den1, idx2, sigma, accPix, Xacc, Wacc);
        fold_div_kernel<<<(imgTotal + 255) / 256, 256, 0, stream>>>(Xacc, Wacc, out);
    } else {
        const int accTotal = NIMG * IMG_SZ * 2;
        // Round 1: M1=18
        zero_kernel<<<(accTotal + 255) / 256, 256, 0, stream>>>(accPix, accTotal);
        bm_kernel<18><<<dim3(16, 64, NIMG), 256, 0, stream>>>(y, idx1);
        denoise_kernel<18, false, false><<<dim3(NB, NIMG), 128, 0, stream>>>(
            y, y, idx1, sigma, accPix, Xacc, Wacc);
        div_kernel<<<(imgTotal + 255) / 256, 256, 0, stream>>>(accPix, den1, imgTotal);
        // Round 2: M2=55
        zero_kernel<<<(accTotal + 255) / 256, 256, 0, stream>>>(accPix, accTotal);
        bm_kernel<55><<<dim3(16, 64, NIMG), 256, 0, stream>>>(den1, idx2);
        denoise_kernel<55, true, false><<<dim3(NB, NIMG), 128, 0, stream>>>(
            y, den1, idx2, sigma, accPix, Xacc, Wacc);
        div_kernel<<<(imgTotal + 255) / 256, 256, 0, stream>>>(accPix, out, imgTotal);
    }
}

// Round 10
// 948.120 us; speedup vs baseline: 1.7003x; 1.0132x over previous
//
#include <hip/hip_runtime.h>
#include <math.h>

#define IMG_H 256
#define IMG_W 256
#define IMG_SZ (IMG_H * IMG_W)
#define NP 49      /* C*p*p patch vector length */
#define HP 250     /* H - p + 1 */
#define NPAT 62500 /* HP*HP patches per image */
#define NB 4096    /* groups per image = 64*64 */
#define NCAND 1369 /* 37*37 */
#define VRAD 18
#define CENTER (VRAD * 37 + VRAD)
#define NIMG 2
#define YSTR 52    /* patch row stride: 208B, 16B aligned */
#define WSTR 55    /* bm window stride: odd -> conflict-free */

// Map aligned-patch coordinates (253x253, after align_corners with s=4 on a
// 250x250 grid) to original patch coordinates. Returns false for inf slots.
__device__ __forceinline__ bool align_map(int r, int c, int& ro, int& co) {
    if (r < 0 || r > 252 || c < 0 || c > 252) return false;
    if (r == 252) {
        if (c == 252) { ro = 249; co = 249; return true; }
        if (c <= 248 && (c & 3) == 0) { ro = 249; co = c; return true; }
        return false;
    }
    if (c == 252) {
        if (r <= 248 && (r & 3) == 0) { ro = r; co = 249; return true; }
        return false;
    }
    if (r >= 250 || c >= 250) return false;
    if (r == 249) {
        if (c == 249) return false;
        if ((c & 3) == 0) return false;
        ro = 249; co = c; return true;
    }
    if (c == 249) {
        if ((r & 3) == 0) return false;
        ro = r; co = 249; return true;
    }
    ro = r; co = c; return true;
}

__global__ void zero_kernel(float* __restrict__ p, int total) {
    int i = blockIdx.x * blockDim.x + threadIdx.x;
    if (i < total) p[i] = 0.0f;
}

// PIXEL-mode: acc holds interleaved (num, weight) pairs per pixel.
__global__ void div_kernel(const float* __restrict__ acc, float* __restrict__ out, int total) {
    int i = blockIdx.x * blockDim.x + threadIdx.x;
    if (i < total) out[i] = acc[2 * i] / acc[2 * i + 1];
}

// PATCH-mode fold: one block per 8x8 pixel tile. Stage the 14x14 covering
// patch rows into LDS (coalesced: pc-consecutive patch rows are contiguous
// 686-float spans), then 4 threads/pixel split the 7 ki rows and quad-reduce.
__global__ __launch_bounds__(256) void fold_div_kernel(const float* __restrict__ Xacc,
                                                       const float* __restrict__ Wacc,
                                                       float* __restrict__ out) {
    __shared__ __align__(16) float Xs[196 * 49];
    __shared__ float Ws[196];
    const int tc = blockIdx.x, tr = blockIdx.y, n = blockIdx.z;
    const int r0 = tr * 8, c0 = tc * 8;
    const int pr0 = r0 - 6, pc0 = c0 - 6;
    const int t = threadIdx.x;
    const float* Xn = Xacc + (size_t)n * NPAT * NP;
    const float* Wn = Wacc + (size_t)n * NPAT;
    for (int e = t; e < 196 * 49; e += 256) {
        int pr_l = e / 686, rem = e - pr_l * 686;
        int pc_l = rem / 49, ch = rem - pc_l * 49;
        int pr = pr0 + pr_l, pc = pc0 + pc_l;
        float v = 0.f;
        if (pr >= 0 && pr < HP && pc >= 0 && pc < HP)
            v = Xn[(size_t)(pr * HP + pc) * NP + ch];
        Xs[e] = v;
    }
    for (int e = t; e < 196; e += 256) {
        int pr = pr0 + e / 14, pc = pc0 + e % 14;
        float v = 0.f;
        if (pr >= 0 && pr < HP && pc >= 0 && pc < HP) v = Wn[pr * HP + pc];
        Ws[e] = v;
    }
    __syncthreads();
    const int p = t >> 2, part = t & 3;
    const int prx = p >> 3, pcx = p & 7;  // pixel within tile
    float num = 0.f, den = 0.f;
    const int ki0 = part * 2;
    const int kiN = (part == 3) ? 1 : 2;
    for (int kk = 0; kk < kiN; ++kk) {
        int ki = ki0 + kk;
        int pr_l = prx + 6 - ki;
#pragma unroll
        for (int kj = 0; kj < 7; ++kj) {
            int pc_l = pcx + 6 - kj;
            num += Xs[pr_l * 686 + pc_l * 49 + ki * 7 + kj];
            den += Ws[pr_l * 14 + pc_l];
        }
    }
    num += __shfl_xor(num, 1);
    den += __shfl_xor(den, 1);
    num += __shfl_xor(num, 2);
    den += __shfl_xor(den, 2);
    if (part == 0)
        out[(size_t)n * IMG_SZ + (r0 + prx) * IMG_W + (c0 + pcx)] = num / den;
}

// 4 reference patches per 256-thread block (one wave each), sharing one staged
// union window. refp in registers; center forced during fill; selection via
// barrier-free shfl butterfly over per-lane top-2 caches.
template <int M>
__global__ __launch_bounds__(256) void bm_kernel(const float* __restrict__ img,
                                                 int* __restrict__ idx_out) {
    __shared__ float win[43 * WSTR];
    __shared__ float dist[4][NCAND];
    const int llb = blockIdx.x, kk = blockIdx.y, n = blockIdx.z;
    const float* im = img + (size_t)n * IMG_SZ;
    const int t = threadIdx.x;
    const int w = t >> 6, lane = t & 63;
    const int ll = 4 * llb + w;
    const int rr = (kk < 63) ? 4 * kk : 249;
    const int cc = (ll < 63) ? 4 * ll : 249;
    const int ar0 = 4 * kk, ac0 = 4 * ll;
    const int acb = 16 * llb;
    const int row0 = max(0, ar0 - VRAD), col0 = max(0, acb - VRAD);
    const int row1 = min(IMG_H - 1, ar0 + VRAD + 6);
    const int col1 = min(IMG_W - 1, acb + 12 + VRAD + 6);
    const int nr = row1 - row0 + 1, nc = col1 - col0 + 1;
    for (int e = t; e < nr * nc; e += 256) {
        int r = e / nc, c = e % nc;
        win[r * WSTR + c] = im[(row0 + r) * IMG_W + col0 + c];
    }
    __syncthreads();
    float rf[NP];
    {
        const float* rb = &win[(rr - row0) * WSTR + (cc - col0)];
#pragma unroll
        for (int ki = 0; ki < 7; ++ki)
#pragma unroll
            for (int kj = 0; kj < 7; ++kj) rf[ki * 7 + kj] = rb[ki * WSTR + kj];
    }
    float* dw = dist[w];
    for (int cand = lane; cand < NCAND; cand += 64) {
        const int dr = cand / 37 - VRAD, dc = cand % 37 - VRAD;
        int ro, co;
        float d;
        if (align_map(ar0 + dr, ac0 + dc, ro, co)) {
            const float* base = &win[(ro - row0) * WSTR + (co - col0)];
            float s = 0.f;
#pragma unroll
            for (int ki = 0; ki < 7; ++ki)
#pragma unroll
                for (int kj = 0; kj < 7; ++kj) {
                    float df = base[ki * WSTR + kj] - rf[ki * 7 + kj] + 1e-6f;
                    s = fmaf(df, df, s);
                }
            d = sqrtf(s);
        } else {
            d = INFINITY;
        }
        if (cand == CENTER) d = -1.0f;  // center always wins sel 0
        dw[cand] = d;
    }
    __syncthreads();
    // per-lane top-2 over the strided bucket (ascending scan => ties keep low idx)
    float v1 = INFINITY, v2 = INFINITY;
    int i1 = NCAND, i2 = NCAND;
    for (int c = lane; c < NCAND; c += 64) {
        float v = dw[c];
        if (v < v1) { v2 = v1; i2 = i1; v1 = v; i1 = c; }
        else if (v < v2) { v2 = v; i2 = c; }
    }
    int* out = idx_out + (size_t)((n * 64 + kk) * 64 + ll) * M;
    for (int sel = 0; sel < M; ++sel) {
        float gv = v1;
        int gi = i1;
#pragma unroll
        for (int off = 32; off; off >>= 1) {
            float vv = __shfl_xor(gv, off);
            int ii = __shfl_xor(gi, off);
            if (vv < gv || (vv == gv && ii < gi)) { gv = vv; gi = ii; }
        }
        if (lane == 0) {
            int dr = gi / 37 - VRAD, dc = gi % 37 - VRAD;
            out[sel] = min(rr + dr, 249) * HP + min(cc + dc, 249);
        }
        if ((gi & 63) == lane) {  // owner pops its cache; rescan only if exhausted
            dw[gi] = INFINITY;
            v1 = v2; i1 = i2; v2 = INFINITY; i2 = NCAND;
            if (i1 == NCAND) {
                for (int c = lane; c < NCAND; c += 64) {
                    float v = dw[c];
                    if (v < v1) { v2 = v1; i2 = i1; v1 = v; i1 = c; }
                    else if (v < v2) { v2 = v; i2 = c; }
                }
            }
        }
    }
}

// 128 threads (2 waves) per group. theta = I - c*A^-1 in BOTH rounds.
// LDS union SU = [packed-L (16B-aligned rows) | Ys rows]: R2 stages Xs over
// the L region during Gram (L written after the sync), Ys staged post-Gram.
// Peak LDS ~19KB -> 8 blocks/CU. Gram slot-distributed -> packed A; Cholesky
// wave0-only, rows in registers (d^2 form, row reconstructed from packed
// symmetry), zero barriers; scaled packed L stored once. Solve: wave0 = M
// identity cols (weights), wave1 = 49 Y cols (X_hat); uniform broadcast
// float4 L reads at constexpr packed offsets. Epilogue: per-PATCH atomics
// (AGGP) or per-pixel fallback.
template <int M, bool R2, bool AGGP>
__global__ __launch_bounds__(128, 2) void denoise_kernel(
    const float* __restrict__ y, const float* __restrict__ xsrc,
    const int* __restrict__ idx, const float* __restrict__ sigma_p,
    float* __restrict__ accPix, float* __restrict__ Xacc, float* __restrict__ Wacc) {
    constexpr int PADM = (M + 3) & ~3;  // 56 for M=55, 20 for M=18
    constexpr int NCH = PADM / 4;
    constexpr int TPK = M * (M + 1) / 2;
    constexpr int NS = (TPK + 127) / 128;
    // packed row offset (floats), each row 16B aligned: sum_{k<i} roundup4(k+1)
    struct RO { static constexpr int f(int i) {
        int a = i >> 2, b = i & 3; return 8 * a * (a + 1) + 4 * (a + 1) * b; } };
    constexpr int LSZ = RO::f(PADM);
    constexpr int YOFF = LSZ;            // Ys rows live after the packed L
    constexpr int UN = LSZ + M * YSTR;   // union size (floats)
    __shared__ __align__(16) float SU[UN];
    __shared__ float cbuf[64];
    __shared__ __align__(16) float rdiag[PADM];
    __shared__ float wsh[M];
    __shared__ int gix[M];
    const int b = blockIdx.x, n = blockIdx.y;
    const int t = threadIdx.x;
    const int lane = t & 63, wv = t >> 6;
    if (t < M) gix[t] = idx[(size_t)(n * NB + b) * M + t];
    __syncthreads();
    const float* im = y + (size_t)n * IMG_SZ;
    const float* xim = xsrc + (size_t)n * IMG_SZ;
    // --- stage Gram source rows (R1: Ys at YOFF; R2: Xs at 0) ---
    {
        const float* src = R2 ? xim : im;
        float* dst = R2 ? &SU[0] : &SU[YOFF];
        for (int e = t; e < M * YSTR; e += 128) {
            int i = e / YSTR, ch = e - i * YSTR;
            float v = 0.f;
            if (ch < NP) {
                int p = gix[i];
                v = src[(p / HP + ch / 7) * IMG_W + (p % HP + ch % 7)];
            }
            dst[i * YSTR + ch] = v;
        }
    }
    __syncthreads();
    const float sg = sigma_p[0];
    const float cns = 49.f * sg * sg;
    // --- Gram, slot-distributed over 128 threads, results in registers ---
    int siR[NS], sjR[NS];
    float gsum[NS];
#pragma unroll
    for (int s = 0; s < NS; ++s) {
        int e = t + 128 * s;
        if (e < TPK) {
            int i = (int)((sqrtf(8.f * e + 1.f) - 1.f) * 0.5f);
            while ((i + 1) * (i + 2) / 2 <= e) ++i;
            while (i * (i + 1) / 2 > e) --i;
            siR[s] = i;
            sjR[s] = e - i * (i + 1) / 2;
        } else {
            siR[s] = -1;
            sjR[s] = 0;
        }
    }
    {
        const float* base = R2 ? &SU[0] : &SU[YOFF];
#pragma unroll
        for (int s = 0; s < NS; ++s) {
            float sum = 0.f;
            if (siR[s] >= 0) {
                const float* Pi = base + siR[s] * YSTR;
                const float* Pj = base + sjR[s] * YSTR;
#pragma unroll
                for (int q = 0; q < 13; ++q) {
                    float4 a = *(const float4*)(Pi + 4 * q);
                    float4 c4 = *(const float4*)(Pj + 4 * q);
                    sum = fmaf(a.x, c4.x, sum);
                    sum = fmaf(a.y, c4.y, sum);
                    sum = fmaf(a.z, c4.z, sum);
                    sum = fmaf(a.w, c4.w, sum);
                }
                if (R2 && siR[s] == sjR[s]) sum += cns;
            }
            gsum[s] = sum;
        }
    }
    __syncthreads();  // all Gram reads complete before A overlays Xs region
    // --- write packed A; R2: stage Ys (overwrites dead Xs tail) ---
#pragma unroll
    for (int s = 0; s < NS; ++s)
        if (siR[s] >= 0) SU[RO::f(siR[s]) + sjR[s]] = gsum[s];
    if (R2) {
        for (int e = t; e < M * YSTR; e += 128) {
            int i = e / YSTR, ch = e - i * YSTR;
            float v = 0.f;
            if (ch < NP) {
                int p = gix[i];
                v = im[(p / HP + ch / 7) * IMG_W + (p % HP + ch % 7)];
            }
            SU[YOFF + i * YSTR + ch] = v;
        }
    }
    __syncthreads();
    // --- wave0: register-row Cholesky (d^2 form), zero barriers ---
    if (wv == 0) {
        float g[PADM];
        if (lane < M) {
#pragma unroll
            for (int j = 0; j < PADM; ++j) {
                if (j >= M) g[j] = 0.f;
                else g[j] = (j <= lane) ? SU[RO::f(lane) + j] : SU[RO::f(j) + lane];
            }
        } else {
#pragma unroll
            for (int j = 0; j < PADM; ++j) g[j] = (j == lane) ? 1.f : 0.f;
        }
#pragma unroll
        for (int k = 0; k < PADM - 1; ++k) {
            cbuf[lane] = g[k];
            float ivd = 1.f / cbuf[k];
            float fk = g[k] * ivd;
#pragma unroll
            for (int jb = (k + 1) / 4; jb < NCH; ++jb) {
                float4 cv = *(const float4*)&cbuf[4 * jb];
                if (4 * jb + 0 > k) g[4 * jb + 0] = fmaf(-fk, cv.x, g[4 * jb + 0]);
                if (4 * jb + 1 > k) g[4 * jb + 1] = fmaf(-fk, cv.y, g[4 * jb + 1]);
                if (4 * jb + 2 > k) g[4 * jb + 2] = fmaf(-fk, cv.z, g[4 * jb + 2]);
                if (4 * jb + 3 > k) g[4 * jb + 3] = fmaf(-fk, cv.w, g[4 * jb + 3]);
            }
        }
        if (lane < PADM) rdiag[lane] = (lane < M) ? 1.f / sqrtf(g[lane]) : 1.f;
        // scale row by rdiag[col], store packed L (only j<=i read by solves)
        if (lane < PADM) {
#pragma unroll
            for (int jb = 0; jb < NCH; ++jb) {
                if (4 * jb <= lane) {
                    float4 rd4 = *(const float4*)&rdiag[4 * jb];
                    float4 o;
                    o.x = g[4 * jb + 0] * rd4.x;
                    o.y = g[4 * jb + 1] * rd4.y;
                    o.z = g[4 * jb + 2] * rd4.z;
                    o.w = g[4 * jb + 3] * rd4.w;
                    *(float4*)&SU[RO::f(lane) + 4 * jb] = o;
                }
            }
        }
    }
    __syncthreads();
    // --- solves: wave0 lane -> identity col (weights), wave1 lane -> Y col ---
    const bool isId = (wv == 0) && (lane < M);
    const bool isY = (wv == 1) && (lane < NP);
    const int ch = (wv == 1 && lane < NP) ? lane : 0;
    float bb[PADM];
    if (wv == 1) {
#pragma unroll
        for (int i = 0; i < PADM; ++i) bb[i] = (i < M) ? SU[YOFF + i * YSTR + ch] : 0.f;
    } else {
#pragma unroll
        for (int i = 0; i < PADM; ++i) bb[i] = (i == lane) ? 1.f : 0.f;
    }
    // forward: L z = b, 4-wide chunks; all L loads wave-uniform broadcasts
#pragma unroll
    for (int ck = 0; ck < NCH; ++ck) {
        const int i0 = 4 * ck;
        float L10 = SU[RO::f(4 * ck + 1) + 4 * ck];
        float L20 = SU[RO::f(4 * ck + 2) + 4 * ck], L21 = SU[RO::f(4 * ck + 2) + 4 * ck + 1];
        float L30 = SU[RO::f(4 * ck + 3) + 4 * ck], L31 = SU[RO::f(4 * ck + 3) + 4 * ck + 1],
              L32 = SU[RO::f(4 * ck + 3) + 4 * ck + 2];
        float b0 = bb[i0] * rdiag[i0];
        float b1 = (bb[i0 + 1] - L10 * b0) * rdiag[i0 + 1];
        float b2 = (bb[i0 + 2] - L20 * b0 - L21 * b1) * rdiag[i0 + 2];
        float b3 = (bb[i0 + 3] - L30 * b0 - L31 * b1 - L32 * b2) * rdiag[i0 + 3];
        bb[i0] = b0; bb[i0 + 1] = b1; bb[i0 + 2] = b2; bb[i0 + 3] = b3;
#pragma unroll
        for (int j = 4 * ck + 4; j < PADM; ++j) {
            float4 L4 = *(const float4*)&SU[RO::f(j) + 4 * ck];
            bb[j] = fmaf(-L4.x, b0, fmaf(-L4.y, b1, fmaf(-L4.z, b2, fmaf(-L4.w, b3, bb[j]))));
        }
        if (ck & 1) asm volatile("" ::: "memory");  // 2-chunk load-hoist window
    }
    // backward: L^T x = z, row sweeps as aligned float4 + compile-time tails
#pragma unroll
    for (int i = PADM - 1; i >= 0; --i) {
        float bbi = bb[i] * rdiag[i];
        bb[i] = bbi;
#pragma unroll
        for (int qb = 0; qb < i / 4; ++qb) {
            float4 L4 = *(const float4*)&SU[RO::f(i) + 4 * qb];
            bb[4 * qb + 0] = fmaf(-L4.x, bbi, bb[4 * qb + 0]);
            bb[4 * qb + 1] = fmaf(-L4.y, bbi, bb[4 * qb + 1]);
            bb[4 * qb + 2] = fmaf(-L4.z, bbi, bb[4 * qb + 2]);
            bb[4 * qb + 3] = fmaf(-L4.w, bbi, bb[4 * qb + 3]);
        }
#pragma unroll
        for (int j = i & ~3; j < i; ++j)
            bb[j] = fmaf(-SU[RO::f(i) + j], bbi, bb[j]);
        if ((i & 7) == 0) asm volatile("" ::: "memory");  // 8-row hoist window
    }
    // --- weights (theta symmetric via identity columns) ---
    float wloc = 0.f;
    if (isId) {
        float s2 = 0.f;
#pragma unroll
        for (int i = 0; i < M; ++i) {
            float th = ((i == lane) ? 1.f : 0.f) - cns * bb[i];
            s2 = fmaf(th, th, s2);
        }
        s2 = fminf(fmaxf(s2, 1.f / (float)M), 1.f);
        wloc = 1.f / s2;
        wsh[lane] = wloc;
    }
    if (!AGGP && isY) {
#pragma unroll
        for (int i = 0; i < M; ++i)
            SU[YOFF + i * YSTR + ch] = fmaf(-cns, bb[i], SU[YOFF + i * YSTR + ch]);
    }
    __syncthreads();
    if (AGGP) {
        // per-PATCH scatter: ~7-way contention, lane-coalesced Xacc lines
        if (isId) atomicAdd(&Wacc[(size_t)n * NPAT + gix[lane]], wloc);
        if (isY) {
#pragma unroll
            for (int i = 0; i < M; ++i) {
                float xv = fmaf(-cns, bb[i], SU[YOFF + i * YSTR + ch]);
                atomicAdd(&Xacc[((size_t)n * NPAT + gix[i]) * NP + ch], xv * wsh[i]);
            }
        }
    } else {
        float* aA = accPix + (size_t)n * IMG_SZ * 2;
        for (int e = t; e < M * NP; e += 128) {
            int i = e / NP, c2 = e % NP;
            int p = gix[i];
            int pix = (p / HP + c2 / 7) * IMG_W + (p % HP + c2 % 7);
            float wi = wsh[i];
            atomicAdd(&aA[pix * 2], SU[YOFF + i * YSTR + c2] * wi);
            atomicAdd(&aA[pix * 2 + 1], wi);
        }
    }
}

extern "C" void kernel_launch(void* const* d_in, const int* in_sizes, int n_in,
                              void* d_out, int out_size, void* d_ws, size_t ws_size,
                              hipStream_t stream) {
    const float* y = (const float*)d_in[0];
    const float* sigma = (const float*)d_in[1];
    float* out = (float*)d_out;

    char* ws = (char*)d_ws;
    size_t off = 0;
    auto carve = [&](size_t bytes) {
        void* p = ws + off;
        off += (bytes + 255) & ~(size_t)255;
        return p;
    };
    int* idx1 = (int*)carve((size_t)NIMG * NB * 18 * sizeof(int));
    int* idx2 = (int*)carve((size_t)NIMG * NB * 55 * sizeof(int));
    float* accPix = (float*)carve((size_t)NIMG * IMG_SZ * 2 * sizeof(float));
    float* den1 = (float*)carve((size_t)NIMG * IMG_SZ * sizeof(float));
    // PATCH-mode accumulators: X then W contiguous (zeroed together)
    const size_t xw_floats = (size_t)NIMG * NPAT * (NP + 1);
    float* Xacc = (float*)carve(xw_floats * sizeof(float));
    float* Wacc = Xacc + (size_t)NIMG * NPAT * NP;
    const bool patchMode = (off <= ws_size);

    const int imgTotal = NIMG * IMG_SZ;

    if (patchMode) {
        const int xwTotal = (int)xw_floats;
        // Round 1: M1=18
        zero_kernel<<<(xwTotal + 255) / 256, 256, 0, stream>>>(Xacc, xwTotal);
        bm_kernel<18><<<dim3(16, 64, NIMG), 256, 0, stream>>>(y, idx1);
        denoise_kernel<18, false, true><<<dim3(NB, NIMG), 128, 0, stream>>>(
            y, y, idx1, sigma, accPix, Xacc, Wacc);
        fold_div_kernel<<<dim3(32, 32, NIMG), 256, 0, stream>>>(Xacc, Wacc, den1);
        // Round 2: M2=55
        zero_kernel<<<(xwTotal + 255) / 256, 256, 0, stream>>>(Xacc, xwTotal);
        bm_kernel<55><<<dim3(16, 64, NIMG), 256, 0, stream>>>(den1, idx2);
        denoise_kernel<55, true, true><<<dim3(NB, NIMG), 128, 0, stream>>>(
            y, den1, idx2, sigma, accPix, Xacc, Wacc);
        fold_div_kernel<<<dim3(32, 32, NIMG), 256, 0, stream>>>(Xacc, Wacc, out);
    } else {
        const int accTotal = NIMG * IMG_SZ * 2;
        // Round 1: M1=18
        zero_kernel<<<(accTotal + 255) / 256, 256, 0, stream>>>(accPix, accTotal);
        bm_kernel<18><<<dim3(16, 64, NIMG), 256, 0, stream>>>(y, idx1);
        denoise_kernel<18, false, false><<<dim3(NB, NIMG), 128, 0, stream>>>(
            y, y, idx1, sigma, accPix, Xacc, Wacc);
        div_kernel<<<(imgTotal + 255) / 256, 256, 0, stream>>>(accPix, den1, imgTotal);
        // Round 2: M2=55
        zero_kernel<<<(accTotal + 255) / 256, 256, 0, stream>>>(accPix, accTotal);
        bm_kernel<55><<<dim3(16, 64, NIMG), 256, 0, stream>>>(den1, idx2);
        denoise_kernel<55, true, false><<<dim3(NB, NIMG), 128, 0, stream>>>(
            y, den1, idx2, sigma, accPix, Xacc, Wacc);
        div_kernel<<<(imgTotal + 255) / 256, 256, 0, stream>>>(accPix, out, imgTotal);
    }
}